// Round 5
// baseline (1203.260 us; speedup 1.0000x reference)
//
#include <hip/hip_runtime.h>
#include <hip/hip_bf16.h>
#include <cstdint>
#include <cstddef>

// Problem constants
#define NF 128        // F
#define N_EDGES 100000
#define N_ANGLES 400000
#define N_CRYST 512
#define KDIM 320      // 2F + A
#define TWOF 256
#define EPS_LN 1e-5f
#define INV_SQRT_2 0.70710678118654752440f

typedef short short8 __attribute__((ext_vector_type(8)));
typedef float floatx4 __attribute__((ext_vector_type(4)));

// ---------------- helpers ----------------
__device__ inline unsigned short f2bf(float x) {
    __hip_bfloat16 b = __float2bfloat16(x);
    return *reinterpret_cast<unsigned short*>(&b);
}
__device__ inline float bf2f(__hip_bfloat16 b) { return __bfloat162float(b); }
__device__ inline float bfbits2f(unsigned short u) {
    unsigned int v = ((unsigned int)u) << 16;
    return __uint_as_float(v);
}

__device__ inline uint4 cvt8(float4 a, float4 b) {
    __hip_bfloat162 p0 = __float22bfloat162_rn(make_float2(a.x, a.y));
    __hip_bfloat162 p1 = __float22bfloat162_rn(make_float2(a.z, a.w));
    __hip_bfloat162 p2 = __float22bfloat162_rn(make_float2(b.x, b.y));
    __hip_bfloat162 p3 = __float22bfloat162_rn(make_float2(b.z, b.w));
    uint4 r;
    r.x = *reinterpret_cast<unsigned int*>(&p0);
    r.y = *reinterpret_cast<unsigned int*>(&p1);
    r.z = *reinterpret_cast<unsigned int*>(&p2);
    r.w = *reinterpret_cast<unsigned int*>(&p3);
    return r;
}

// ---------------- kernel 0: pre-pack W_full -> bf16, LDS-staging order ----------------
// Plane ki (16 KB): slot s in [0,1024): n = s>>2, kc = s&3,
// holds W[n][ki*32 + (kc^((n>>1)&3))*8 .. +8) as bf16x8.
__global__ __launch_bounds__(256) void w_pack(const float* __restrict__ W_full,
                                              uint4* __restrict__ wsW) {
    int s  = blockIdx.x * 256 + threadIdx.x;   // 0..10239
    int ki = s >> 10;
    int sl = s & 1023;
    int n  = sl >> 2, kc = sl & 3;
    int ko = (kc ^ ((n >> 1) & 3)) * 8;
    const float* src = W_full + (size_t)n * KDIM + ki * 32 + ko;
    wsW[s] = cvt8(((const float4*)src)[0], ((const float4*)src)[1]);
}

// ---------------- kernel 1: segment boundaries (sorted crystal_angle_index) ----------------
__global__ void seg_bounds(const int* __restrict__ seg, int* __restrict__ seg_start) {
    int s = blockIdx.x * blockDim.x + threadIdx.x;
    if (s > N_CRYST) return;
    if (s == N_CRYST) { seg_start[N_CRYST] = N_ANGLES; return; }
    int lo = 0, hi = N_ANGLES;
    while (lo < hi) { int mid = (lo + hi) >> 1; if (seg[mid] < s) lo = mid + 1; else hi = mid; }
    seg_start[s] = lo;
}

// ---------------- kernel 2: fused gather + GEMM via bf16 MFMA (v3) ----------------
// 64 rows x 256 cols per block, 256 threads (4 waves).
// Phase A: burst-gather ALL of X (64x320) into LDS (10 independent 32B loads/thread
//          -> one latency exposure, high MLP).
// K-loop: X from resident LDS; W streamed from pre-packed bf16 ws copy through a
//         double-buffered LDS stage, prefetched one iter ahead (L2-hit, hidden by MFMA).
__global__ __launch_bounds__(256) void gemm_gather_mfma(
    const float* __restrict__ angle_fea,      // N_ANGLES x 64
    const float* __restrict__ nbr_fea,        // N_EDGES x 128
    const int*   __restrict__ angle_nbr_idx,  // N_ANGLES x 2
    const uint4* __restrict__ wsW,            // pre-packed bf16 W (10 planes x 16 KB)
    __hip_bfloat16* __restrict__ hout)        // N_ANGLES x 256
{
    __shared__ uint4 X_lds[2560];      // 10 planes x 64 rows x 32 k bf16 (40 KB)
    __shared__ uint4 W_lds[2][1024];   // dbuf: 256 n x 32 k bf16 (16 KB each)

    const int tid  = threadIdx.x;
    const int row0 = blockIdx.x * 64;    // 6250 blocks, exact

    // ---- phase A: burst X ----
    const int xm = tid >> 2;                          // row 0..63
    const int xko = ((tid & 3) ^ ((xm >> 1) & 3)) * 8; // swizzled k-elem offset in [0,32)
    const int p0 = angle_nbr_idx[(size_t)(row0 + xm) * 2 + 0];
    const int p1 = angle_nbr_idx[(size_t)(row0 + xm) * 2 + 1];

    float4 ra[10], rb[10];
    #pragma unroll
    for (int ki = 0; ki < 10; ++ki) {
        const int kb = ki * 32;
        const float* src;
        if (kb < 64)       src = angle_fea + (size_t)(row0 + xm) * 64 + kb + xko;
        else if (kb < 192) src = nbr_fea + (size_t)p0 * 128 + (kb - 64) + xko;
        else               src = nbr_fea + (size_t)p1 * 128 + (kb - 192) + xko;
        ra[ki] = ((const float4*)src)[0];
        rb[ki] = ((const float4*)src)[1];
    }
    #pragma unroll
    for (int ki = 0; ki < 10; ++ki)
        X_lds[ki * 256 + tid] = cvt8(ra[ki], rb[ki]);

    // ---- stage W plane 0 ----
    {
        uint4 w0[4];
        #pragma unroll
        for (int it = 0; it < 4; ++it) w0[it] = wsW[it * 256 + tid];
        #pragma unroll
        for (int it = 0; it < 4; ++it) W_lds[0][it * 256 + tid] = w0[it];
    }
    __syncthreads();

    const int wave = tid >> 6, lane = tid & 63;
    const int wcol = wave * 64;                 // n-quadrant
    const int rl   = lane & 15, kgrp = lane >> 4;
    const int fragoff = (kgrp ^ ((rl >> 1) & 3)) * 16;  // swizzled byte offset
    const char* Xb = (const char*)X_lds;

    floatx4 acc[4][4];
    #pragma unroll
    for (int i = 0; i < 4; ++i)
        #pragma unroll
        for (int j = 0; j < 4; ++j)
            acc[i][j] = (floatx4){0.f, 0.f, 0.f, 0.f};

    #pragma unroll
    for (int ki = 0; ki < 10; ++ki) {
        uint4 wnext[4];
        if (ki < 9) {
            #pragma unroll
            for (int it = 0; it < 4; ++it)
                wnext[it] = wsW[(ki + 1) * 1024 + it * 256 + tid];
        }
        const char* Wb = (const char*)&W_lds[ki & 1][0];
        short8 wf[4], xf[4];
        #pragma unroll
        for (int i = 0; i < 4; ++i)
            wf[i] = *(const short8*)(Wb + (size_t)(wcol + i * 16 + rl) * 64 + fragoff);
        #pragma unroll
        for (int j = 0; j < 4; ++j)
            xf[j] = *(const short8*)(Xb + (size_t)ki * 4096 + (size_t)(j * 16 + rl) * 64 + fragoff);
        #pragma unroll
        for (int i = 0; i < 4; ++i)
            #pragma unroll
            for (int j = 0; j < 4; ++j)
                acc[i][j] = __builtin_amdgcn_mfma_f32_16x16x32_bf16(wf[i], xf[j], acc[i][j], 0, 0, 0);
        if (ki < 9) {
            #pragma unroll
            for (int it = 0; it < 4; ++it)
                W_lds[(ki + 1) & 1][it * 256 + tid] = wnext[it];
            __syncthreads();
        }
    }

    // ---- epilogue: D[n][m] -> h[m][n]; lane holds 4 consecutive n per (i,j)
    unsigned short* hp = reinterpret_cast<unsigned short*>(hout);
    #pragma unroll
    for (int j = 0; j < 4; ++j) {
        size_t r = (size_t)(row0 + j * 16 + rl);
        #pragma unroll
        for (int i = 0; i < 4; ++i) {
            int c = wcol + i * 16 + kgrp * 4;
            floatx4 v = acc[i][j];
            uint2 pk;
            pk.x = (unsigned int)f2bf(v[0]) | ((unsigned int)f2bf(v[1]) << 16);
            pk.y = (unsigned int)f2bf(v[2]) | ((unsigned int)f2bf(v[3]) << 16);
            *reinterpret_cast<uint2*>(hp + r * TWOF + c) = pk;
        }
    }
}

// ---------------- kernel 3: per-segment sum / sumsq (vectorized 16B/lane) ----------------
__global__ __launch_bounds__(256) void seg_stats(
    const __hip_bfloat16* __restrict__ h,
    const int* __restrict__ seg_start,
    float* __restrict__ segSum, float* __restrict__ segSumSq)
{
    __shared__ float redS[8][256];
    __shared__ float redQ[8][256];
    int seg   = blockIdx.x;
    int split = blockIdx.y;  // 0..3
    int start = seg_start[seg], end = seg_start[seg + 1];
    int n = end - start;
    int g = threadIdx.x >> 5, t = threadIdx.x & 31;
    float s[8] = {0.f,0.f,0.f,0.f,0.f,0.f,0.f,0.f};
    float q[8] = {0.f,0.f,0.f,0.f,0.f,0.f,0.f,0.f};
    if (n > 0) {
        int per = (n + 3) >> 2;
        int r0 = start + split * per;
        int r1 = min(r0 + per, end);
        const unsigned short* hp = (const unsigned short*)h;
        for (int r = r0 + g; r < r1; r += 8) {
            uint4 v = *(const uint4*)(hp + (size_t)r * TWOF + t * 8);
            unsigned int d[4] = {v.x, v.y, v.z, v.w};
            #pragma unroll
            for (int i = 0; i < 4; ++i) {
                float lo = __uint_as_float(d[i] << 16);
                float hi = __uint_as_float(d[i] & 0xffff0000u);
                s[2*i]   += lo; q[2*i]   += lo * lo;
                s[2*i+1] += hi; q[2*i+1] += hi * hi;
            }
        }
    }
    #pragma unroll
    for (int i = 0; i < 8; ++i) { redS[g][t * 8 + i] = s[i]; redQ[g][t * 8 + i] = q[i]; }
    __syncthreads();
    if (n > 0) {
        int col = threadIdx.x;
        float S = 0.f, Q = 0.f;
        #pragma unroll
        for (int gg = 0; gg < 8; ++gg) { S += redS[gg][col]; Q += redQ[gg][col]; }
        atomicAdd(&segSum[seg * TWOF + col], S);
        atomicAdd(&segSumSq[seg * TWOF + col], Q);
    }
}

// ---------------- kernel 4: finalize mean / rsqrt(var+eps) in place ----------------
__global__ __launch_bounds__(256) void seg_finalize(
    const int* __restrict__ seg_start,
    float* __restrict__ segSum, float* __restrict__ segSumSq)
{
    int seg = blockIdx.x;
    int j = threadIdx.x;
    float cnt = (float)max(seg_start[seg + 1] - seg_start[seg], 1);
    float inv = 1.0f / cnt;
    float mean = segSum[seg * TWOF + j] * inv;
    float var  = segSumSq[seg * TWOF + j] * inv - mean * mean;
    segSum[seg * TWOF + j]   = mean;
    segSumSq[seg * TWOF + j] = rsqrtf(var + EPS_LN);
}

// ---------------- kernel 5: per-angle normalize + LN(core) + gate + scatter (v2) ----------------
// 1 wave/row; lane owns 4 consecutive cols (uint2 h-read). Lanes 0-31 = core half
// (LN + silu + scatter), lanes 32-63 = filter half (gate dot). Half-wave reductions.
__global__ __launch_bounds__(256) void angle_msg(
    const __hip_bfloat16* __restrict__ h,
    const int* __restrict__ seg_idx,
    const int* __restrict__ angle_nbr_idx,
    const float* __restrict__ segMean, const float* __restrict__ segScale,
    const float* __restrict__ cn_gamma, const float* __restrict__ cn_beta,
    const float* __restrict__ ln_g, const float* __restrict__ ln_b,
    const float* __restrict__ w_mask,
    float* __restrict__ s_acc, float* __restrict__ c_acc)
{
    int row  = blockIdx.x * 4 + (threadIdx.x >> 6);
    int lane = threadIdx.x & 63;
    int seg  = seg_idx[row];
    int src  = angle_nbr_idx[(size_t)row * 2];
    int c4   = lane * 4;

    uint2 hv = *(const uint2*)((const unsigned short*)h + (size_t)row * TWOF + c4);
    float y[4];
    y[0] = __uint_as_float(hv.x << 16);
    y[1] = __uint_as_float(hv.x & 0xffff0000u);
    y[2] = __uint_as_float(hv.y << 16);
    y[3] = __uint_as_float(hv.y & 0xffff0000u);

    float4 m4 = *(const float4*)&segMean[seg * TWOF + c4];
    float4 s4 = *(const float4*)&segScale[seg * TWOF + c4];
    float4 g4 = *(const float4*)&cn_gamma[c4];
    float4 b4 = *(const float4*)&cn_beta[c4];
    y[0] = (y[0] - m4.x) * s4.x * g4.x + b4.x;
    y[1] = (y[1] - m4.y) * s4.y * g4.y + b4.y;
    y[2] = (y[2] - m4.z) * s4.z * g4.z + b4.z;
    y[3] = (y[3] - m4.w) * s4.w * g4.w + b4.w;

    float sum, ssq, gp;
    if (lane < 32) {
        sum = y[0] + y[1] + y[2] + y[3];
        ssq = y[0]*y[0] + y[1]*y[1] + y[2]*y[2] + y[3]*y[3];
        gp  = 0.f;
    } else {
        float4 wm = *(const float4*)&w_mask[c4 - 128];
        gp  = y[0]*wm.x + y[1]*wm.y + y[2]*wm.z + y[3]*wm.w;
        sum = 0.f; ssq = 0.f;
    }
    #pragma unroll
    for (int o = 16; o > 0; o >>= 1) {
        sum += __shfl_xor(sum, o, 64);
        ssq += __shfl_xor(ssq, o, 64);
        gp  += __shfl_xor(gp,  o, 64);
    }
    float gate = 1.f / (1.f + __expf(-__shfl(gp, 32, 64)));

    if (lane < 32) {
        float mu  = sum * (1.f / 128.f);
        float var = ssq * (1.f / 128.f) - mu * mu;
        float rs  = rsqrtf(var + EPS_LN);
        float4 lg = *(const float4*)&ln_g[c4];
        float4 lb = *(const float4*)&ln_b[c4];
        float l0 = (y[0] - mu) * rs * lg.x + lb.x;
        float l1 = (y[1] - mu) * rs * lg.y + lb.y;
        float l2 = (y[2] - mu) * rs * lg.z + lb.z;
        float l3 = (y[3] - mu) * rs * lg.w + lb.w;
        float* d = &s_acc[(size_t)src * NF + c4];
        atomicAdd(d + 0, gate * (l0 / (1.f + __expf(-l0))));
        atomicAdd(d + 1, gate * (l1 / (1.f + __expf(-l1))));
        atomicAdd(d + 2, gate * (l2 / (1.f + __expf(-l2))));
        atomicAdd(d + 3, gate * (l3 / (1.f + __expf(-l3))));
    } else if (lane == 32) {
        atomicAdd(&c_acc[src], 1.0f);
    }
}

// ---------------- kernel 6: edge MLP via bf16 MFMA ----------------
#define MT 64
#define XBS 136
#define H1S 72
#define W1S 136
#define W2S 72
__global__ __launch_bounds__(256) void edge_mlp_mfma(
    const float* __restrict__ s_acc, const float* __restrict__ c_acc,
    const float* __restrict__ nbr_fea,
    const float* __restrict__ ln2_g, const float* __restrict__ ln2_b,
    const float* __restrict__ W1a, const float* __restrict__ b1a,
    const float* __restrict__ W2a, const float* __restrict__ b2a,
    const float* __restrict__ W1b, const float* __restrict__ b1b,
    const float* __restrict__ W2b, const float* __restrict__ b2b,
    float* __restrict__ out)
{
    __shared__ unsigned short xb[MT * XBS];
    __shared__ unsigned short h1[MT * H1S];
    __shared__ unsigned short wl[128 * W2S];

    const int tid  = threadIdx.x;
    const int row0 = blockIdx.x * MT;
    const int w    = tid >> 6, lane = tid & 63;
    const int rl   = lane & 15, kgrp = lane >> 4;

    {
        int m = tid >> 2;
        int q = tid & 3;
        int e = min(row0 + m, N_EDGES - 1);
        float inv = 1.f / fmaxf(c_acc[e], 1.f);
        const float4* src = (const float4*)(s_acc + (size_t)e * NF + q * 32);
        float v[32];
        float sum = 0.f, ssq = 0.f;
        #pragma unroll
        for (int t = 0; t < 8; ++t) {
            float4 f = src[t];
            v[4*t+0] = f.x * inv; v[4*t+1] = f.y * inv; v[4*t+2] = f.z * inv; v[4*t+3] = f.w * inv;
        }
        #pragma unroll
        for (int i = 0; i < 32; ++i) { sum += v[i]; ssq += v[i] * v[i]; }
        sum += __shfl_xor(sum, 1, 64); ssq += __shfl_xor(ssq, 1, 64);
        sum += __shfl_xor(sum, 2, 64); ssq += __shfl_xor(ssq, 2, 64);
        float mu  = sum * (1.f / 128.f);
        float var = ssq * (1.f / 128.f) - mu * mu;
        float rs  = rsqrtf(var + EPS_LN);
        #pragma unroll
        for (int i = 0; i < 32; ++i) {
            int col = q * 32 + i;
            v[i] = (v[i] - mu) * rs * ln2_g[col] + ln2_b[col];
        }
        #pragma unroll
        for (int t = 0; t < 4; ++t) {
            float4 a = make_float4(v[8*t+0], v[8*t+1], v[8*t+2], v[8*t+3]);
            float4 b = make_float4(v[8*t+4], v[8*t+5], v[8*t+6], v[8*t+7]);
            *(uint4*)&xb[m * XBS + q * 32 + t * 8] = cvt8(a, b);
        }
    }

    const float* W1s[2] = {W1a, W1b};
    const float* B1s[2] = {b1a, b1b};
    const float* W2s[2] = {W2a, W2b};
    const float* B2s[2] = {b2a, b2b};

    #pragma unroll 1
    for (int blk = 0; blk < 2; ++blk) {
        const float* W1 = W1s[blk]; const float* B1 = B1s[blk];
        const float* W2 = W2s[blk]; const float* B2 = B2s[blk];

        __syncthreads();
        #pragma unroll
        for (int c = tid; c < 1024; c += 256) {
            int nn = c >> 4, kc = c & 15;
            const float* src = W1 + (size_t)nn * 128 + kc * 8;
            *(uint4*)&wl[nn * W1S + kc * 8] =
                cvt8(((const float4*)src)[0], ((const float4*)src)[1]);
        }
        __syncthreads();

        short8 xf[4];
        #pragma unroll
        for (int ks = 0; ks < 4; ++ks)
            xf[ks] = *(const short8*)&xb[(w * 16 + rl) * XBS + ks * 32 + kgrp * 8];
        floatx4 a1[4];
        #pragma unroll
        for (int i = 0; i < 4; ++i) {
            a1[i] = (floatx4){0.f, 0.f, 0.f, 0.f};
            #pragma unroll
            for (int ks = 0; ks < 4; ++ks) {
                short8 wf = *(const short8*)&wl[(i * 16 + rl) * W1S + ks * 32 + kgrp * 8];
                a1[i] = __builtin_amdgcn_mfma_f32_16x16x32_bf16(wf, xf[ks], a1[i], 0, 0, 0);
            }
        }
        #pragma unroll
        for (int i = 0; i < 4; ++i) {
            int nb = i * 16 + kgrp * 4;
            float s0 = a1[i][0] + B1[nb + 0];
            float s1 = a1[i][1] + B1[nb + 1];
            float s2 = a1[i][2] + B1[nb + 2];
            float s3 = a1[i][3] + B1[nb + 3];
            s0 = s0 / (1.f + __expf(-s0));
            s1 = s1 / (1.f + __expf(-s1));
            s2 = s2 / (1.f + __expf(-s2));
            s3 = s3 / (1.f + __expf(-s3));
            unsigned int lo = (unsigned int)f2bf(s0) | ((unsigned int)f2bf(s1) << 16);
            unsigned int hi = (unsigned int)f2bf(s2) | ((unsigned int)f2bf(s3) << 16);
            *(unsigned int*)&h1[(w * 16 + rl) * H1S + nb]     = lo;
            *(unsigned int*)&h1[(w * 16 + rl) * H1S + nb + 2] = hi;
        }

        __syncthreads();
        #pragma unroll
        for (int c = tid; c < 1024; c += 256) {
            int pp = c >> 3, kc = c & 7;
            const float* src = W2 + (size_t)pp * 64 + kc * 8;
            *(uint4*)&wl[pp * W2S + kc * 8] =
                cvt8(((const float4*)src)[0], ((const float4*)src)[1]);
        }
        __syncthreads();

        short8 hf[2];
        #pragma unroll
        for (int ks = 0; ks < 2; ++ks)
            hf[ks] = *(const short8*)&h1[(w * 16 + rl) * H1S + ks * 32 + kgrp * 8];
        #pragma unroll
        for (int p = 0; p < 8; ++p) {
            floatx4 a2 = (floatx4){0.f, 0.f, 0.f, 0.f};
            #pragma unroll
            for (int ks = 0; ks < 2; ++ks) {
                short8 wf = *(const short8*)&wl[(p * 16 + rl) * W2S + ks * 32 + kgrp * 8];
                a2 = __builtin_amdgcn_mfma_f32_16x16x32_bf16(wf, hf[ks], a2, 0, 0, 0);
            }
            int m = w * 16 + rl;
            #pragma unroll
            for (int reg = 0; reg < 4; ++reg) {
                int pcol = p * 16 + kgrp * 4 + reg;
                int idx  = m * XBS + pcol;
                float xv = bfbits2f(xb[idx]);
                xb[idx] = f2bf(xv + a2[reg] + B2[pcol]);
            }
        }
    }

    {
        int m = tid >> 2;
        int q = tid & 3;
        int e = row0 + m;
        if (e < N_EDGES) {
            const float4* nf = (const float4*)(nbr_fea + (size_t)e * NF + q * 32);
            float4* dst      = (float4*)(out + (size_t)e * NF + q * 32);
            #pragma unroll
            for (int t = 0; t < 8; ++t) {
                float4 f = nf[t];
                int col = q * 32 + 4 * t;
                dst[t] = make_float4(
                    INV_SQRT_2 * (f.x + bfbits2f(xb[m * XBS + col + 0])),
                    INV_SQRT_2 * (f.y + bfbits2f(xb[m * XBS + col + 1])),
                    INV_SQRT_2 * (f.z + bfbits2f(xb[m * XBS + col + 2])),
                    INV_SQRT_2 * (f.w + bfbits2f(xb[m * XBS + col + 3])));
            }
        }
    }
}

// ---------------- workspace layout (bytes) ----------------
//   [0,              524288)   segSum   (512*256 f32)  -> mean after finalize
//   [524288,        1048576)   segSumSq (512*256 f32)  -> scale after finalize
//   [1048576,      52248576)   s_acc    (100000*128 f32)
//   [52248576,     52648576)   c_acc    (100000 f32)
//   --- everything above zeroed each launch ---
//   [52648576,     52652672)   seg_start (513 i32, padded)
//   [52652672,    257452672)   h (400000*256 bf16)
//   [257452672,   257616512)   wsW (pre-packed bf16 W, 10 x 16 KB)

extern "C" void kernel_launch(void* const* d_in, const int* in_sizes, int n_in,
                              void* d_out, int out_size, void* d_ws, size_t ws_size,
                              hipStream_t stream) {
    const float* nbr_fea       = (const float*)d_in[0];
    const float* angle_fea     = (const float*)d_in[1];
    const int*   angle_nbr_idx = (const int*)d_in[2];
    const int*   cai           = (const int*)d_in[4];
    const float* W_full        = (const float*)d_in[5];
    const float* W_mask        = (const float*)d_in[6];
    const float* cn_gamma      = (const float*)d_in[7];
    const float* cn_beta       = (const float*)d_in[8];
    const float* ln_core_g     = (const float*)d_in[9];
    const float* ln_core_b     = (const float*)d_in[10];
    const float* ln2_g         = (const float*)d_in[11];
    const float* ln2_b         = (const float*)d_in[12];
    const float* W1a           = (const float*)d_in[13];
    const float* b1a           = (const float*)d_in[14];
    const float* W2a           = (const float*)d_in[15];
    const float* b2a           = (const float*)d_in[16];
    const float* W1b           = (const float*)d_in[17];
    const float* b1b           = (const float*)d_in[18];
    const float* W2b           = (const float*)d_in[19];
    const float* b2b           = (const float*)d_in[20];
    float* out = (float*)d_out;

    char* ws = (char*)d_ws;
    float* segSum    = (float*)(ws + 0);
    float* segSumSq  = (float*)(ws + 524288);
    float* s_acc     = (float*)(ws + 1048576);
    float* c_acc     = (float*)(ws + 52248576);
    int*   seg_start = (int*)  (ws + 52648576);
    __hip_bfloat16* h = (__hip_bfloat16*)(ws + 52652672);
    uint4* wsW       = (uint4*)(ws + 257452672);

    hipMemsetAsync(ws, 0, 52648576, stream);

    w_pack<<<40, 256, 0, stream>>>(W_full, wsW);
    seg_bounds<<<3, 256, 0, stream>>>(cai, seg_start);
    gemm_gather_mfma<<<N_ANGLES / 64, 256, 0, stream>>>(
        angle_fea, nbr_fea, angle_nbr_idx, wsW, h);
    seg_stats<<<dim3(N_CRYST, 4), 256, 0, stream>>>(h, seg_start, segSum, segSumSq);
    seg_finalize<<<N_CRYST, 256, 0, stream>>>(seg_start, segSum, segSumSq);
    angle_msg<<<N_ANGLES / 4, 256, 0, stream>>>(
        h, cai, angle_nbr_idx, segSum, segSumSq,
        cn_gamma, cn_beta, ln_core_g, ln_core_b, W_mask, s_acc, c_acc);
    edge_mlp_mfma<<<(N_EDGES + MT - 1) / MT, 256, 0, stream>>>(
        s_acc, c_acc, nbr_fea, ln2_g, ln2_b,
        W1a, b1a, W2a, b2a, W1b, b1b, W2b, b2b, out);
}

// Round 6
// 696.427 us; speedup vs baseline: 1.7278x; 1.7278x over previous
//
#include <hip/hip_runtime.h>
#include <hip/hip_bf16.h>
#include <cstdint>
#include <cstddef>

// Problem constants
#define NF 128        // F
#define N_EDGES 100000
#define N_ANGLES 400000
#define N_CRYST 512
#define KDIM 320      // 2F + A
#define TWOF 256
#define EPS_LN 1e-5f
#define INV_SQRT_2 0.70710678118654752440f

typedef short short8 __attribute__((ext_vector_type(8)));
typedef float floatx4 __attribute__((ext_vector_type(4)));

// ---------------- helpers ----------------
__device__ inline unsigned short f2bf(float x) {
    __hip_bfloat16 b = __float2bfloat16(x);
    return *reinterpret_cast<unsigned short*>(&b);
}
__device__ inline float bf2f(__hip_bfloat16 b) { return __bfloat162float(b); }
__device__ inline float bfbits2f(unsigned short u) {
    unsigned int v = ((unsigned int)u) << 16;
    return __uint_as_float(v);
}

__device__ inline uint4 cvt8(float4 a, float4 b) {
    __hip_bfloat162 p0 = __float22bfloat162_rn(make_float2(a.x, a.y));
    __hip_bfloat162 p1 = __float22bfloat162_rn(make_float2(a.z, a.w));
    __hip_bfloat162 p2 = __float22bfloat162_rn(make_float2(b.x, b.y));
    __hip_bfloat162 p3 = __float22bfloat162_rn(make_float2(b.z, b.w));
    uint4 r;
    r.x = *reinterpret_cast<unsigned int*>(&p0);
    r.y = *reinterpret_cast<unsigned int*>(&p1);
    r.z = *reinterpret_cast<unsigned int*>(&p2);
    r.w = *reinterpret_cast<unsigned int*>(&p3);
    return r;
}

// ---------------- kernel 0: pre-pack W_full -> bf16, LDS-staging order ----------------
__global__ __launch_bounds__(256) void w_pack(const float* __restrict__ W_full,
                                              uint4* __restrict__ wsW) {
    int s  = blockIdx.x * 256 + threadIdx.x;   // 0..10239
    int ki = s >> 10;
    int sl = s & 1023;
    int n  = sl >> 2, kc = sl & 3;
    int ko = (kc ^ ((n >> 1) & 3)) * 8;
    const float* src = W_full + (size_t)n * KDIM + ki * 32 + ko;
    wsW[s] = cvt8(((const float4*)src)[0], ((const float4*)src)[1]);
}

// ---------------- kernel 1: segment boundaries (sorted crystal_angle_index) ----------------
__global__ void seg_bounds(const int* __restrict__ seg, int* __restrict__ seg_start) {
    int s = blockIdx.x * blockDim.x + threadIdx.x;
    if (s > N_CRYST) return;
    if (s == N_CRYST) { seg_start[N_CRYST] = N_ANGLES; return; }
    int lo = 0, hi = N_ANGLES;
    while (lo < hi) { int mid = (lo + hi) >> 1; if (seg[mid] < s) lo = mid + 1; else hi = mid; }
    seg_start[s] = lo;
}

// ---------------- kernel 2: fused gather + GEMM via bf16 MFMA (v3) ----------------
__global__ __launch_bounds__(256) void gemm_gather_mfma(
    const float* __restrict__ angle_fea,      // N_ANGLES x 64
    const float* __restrict__ nbr_fea,        // N_EDGES x 128
    const int*   __restrict__ angle_nbr_idx,  // N_ANGLES x 2
    const uint4* __restrict__ wsW,            // pre-packed bf16 W (10 planes x 16 KB)
    __hip_bfloat16* __restrict__ hout)        // N_ANGLES x 256
{
    __shared__ uint4 X_lds[2560];      // 10 planes x 64 rows x 32 k bf16 (40 KB)
    __shared__ uint4 W_lds[2][1024];   // dbuf: 256 n x 32 k bf16 (16 KB each)

    const int tid  = threadIdx.x;
    const int row0 = blockIdx.x * 64;    // 6250 blocks, exact

    const int xm = tid >> 2;
    const int xko = ((tid & 3) ^ ((xm >> 1) & 3)) * 8;
    const int p0 = angle_nbr_idx[(size_t)(row0 + xm) * 2 + 0];
    const int p1 = angle_nbr_idx[(size_t)(row0 + xm) * 2 + 1];

    float4 ra[10], rb[10];
    #pragma unroll
    for (int ki = 0; ki < 10; ++ki) {
        const int kb = ki * 32;
        const float* src;
        if (kb < 64)       src = angle_fea + (size_t)(row0 + xm) * 64 + kb + xko;
        else if (kb < 192) src = nbr_fea + (size_t)p0 * 128 + (kb - 64) + xko;
        else               src = nbr_fea + (size_t)p1 * 128 + (kb - 192) + xko;
        ra[ki] = ((const float4*)src)[0];
        rb[ki] = ((const float4*)src)[1];
    }
    #pragma unroll
    for (int ki = 0; ki < 10; ++ki)
        X_lds[ki * 256 + tid] = cvt8(ra[ki], rb[ki]);

    {
        uint4 w0[4];
        #pragma unroll
        for (int it = 0; it < 4; ++it) w0[it] = wsW[it * 256 + tid];
        #pragma unroll
        for (int it = 0; it < 4; ++it) W_lds[0][it * 256 + tid] = w0[it];
    }
    __syncthreads();

    const int wave = tid >> 6, lane = tid & 63;
    const int wcol = wave * 64;
    const int rl   = lane & 15, kgrp = lane >> 4;
    const int fragoff = (kgrp ^ ((rl >> 1) & 3)) * 16;
    const char* Xb = (const char*)X_lds;

    floatx4 acc[4][4];
    #pragma unroll
    for (int i = 0; i < 4; ++i)
        #pragma unroll
        for (int j = 0; j < 4; ++j)
            acc[i][j] = (floatx4){0.f, 0.f, 0.f, 0.f};

    #pragma unroll
    for (int ki = 0; ki < 10; ++ki) {
        uint4 wnext[4];
        if (ki < 9) {
            #pragma unroll
            for (int it = 0; it < 4; ++it)
                wnext[it] = wsW[(ki + 1) * 1024 + it * 256 + tid];
        }
        const char* Wb = (const char*)&W_lds[ki & 1][0];
        short8 wf[4], xf[4];
        #pragma unroll
        for (int i = 0; i < 4; ++i)
            wf[i] = *(const short8*)(Wb + (size_t)(wcol + i * 16 + rl) * 64 + fragoff);
        #pragma unroll
        for (int j = 0; j < 4; ++j)
            xf[j] = *(const short8*)(Xb + (size_t)ki * 4096 + (size_t)(j * 16 + rl) * 64 + fragoff);
        #pragma unroll
        for (int i = 0; i < 4; ++i)
            #pragma unroll
            for (int j = 0; j < 4; ++j)
                acc[i][j] = __builtin_amdgcn_mfma_f32_16x16x32_bf16(wf[i], xf[j], acc[i][j], 0, 0, 0);
        if (ki < 9) {
            #pragma unroll
            for (int it = 0; it < 4; ++it)
                W_lds[(ki + 1) & 1][it * 256 + tid] = wnext[it];
            __syncthreads();
        }
    }

    unsigned short* hp = reinterpret_cast<unsigned short*>(hout);
    #pragma unroll
    for (int j = 0; j < 4; ++j) {
        size_t r = (size_t)(row0 + j * 16 + rl);
        #pragma unroll
        for (int i = 0; i < 4; ++i) {
            int c = wcol + i * 16 + kgrp * 4;
            floatx4 v = acc[i][j];
            uint2 pk;
            pk.x = (unsigned int)f2bf(v[0]) | ((unsigned int)f2bf(v[1]) << 16);
            pk.y = (unsigned int)f2bf(v[2]) | ((unsigned int)f2bf(v[3]) << 16);
            *reinterpret_cast<uint2*>(hp + r * TWOF + c) = pk;
        }
    }
}

// ---------------- kernel 3: per-segment sum / sumsq (vectorized 16B/lane) ----------------
__global__ __launch_bounds__(256) void seg_stats(
    const __hip_bfloat16* __restrict__ h,
    const int* __restrict__ seg_start,
    float* __restrict__ segSum, float* __restrict__ segSumSq)
{
    __shared__ float redS[8][256];
    __shared__ float redQ[8][256];
    int seg   = blockIdx.x;
    int split = blockIdx.y;  // 0..3
    int start = seg_start[seg], end = seg_start[seg + 1];
    int n = end - start;
    int g = threadIdx.x >> 5, t = threadIdx.x & 31;
    float s[8] = {0.f,0.f,0.f,0.f,0.f,0.f,0.f,0.f};
    float q[8] = {0.f,0.f,0.f,0.f,0.f,0.f,0.f,0.f};
    if (n > 0) {
        int per = (n + 3) >> 2;
        int r0 = start + split * per;
        int r1 = min(r0 + per, end);
        const unsigned short* hp = (const unsigned short*)h;
        for (int r = r0 + g; r < r1; r += 8) {
            uint4 v = *(const uint4*)(hp + (size_t)r * TWOF + t * 8);
            unsigned int d[4] = {v.x, v.y, v.z, v.w};
            #pragma unroll
            for (int i = 0; i < 4; ++i) {
                float lo = __uint_as_float(d[i] << 16);
                float hi = __uint_as_float(d[i] & 0xffff0000u);
                s[2*i]   += lo; q[2*i]   += lo * lo;
                s[2*i+1] += hi; q[2*i+1] += hi * hi;
            }
        }
    }
    #pragma unroll
    for (int i = 0; i < 8; ++i) { redS[g][t * 8 + i] = s[i]; redQ[g][t * 8 + i] = q[i]; }
    __syncthreads();
    if (n > 0) {
        int col = threadIdx.x;
        float S = 0.f, Q = 0.f;
        #pragma unroll
        for (int gg = 0; gg < 8; ++gg) { S += redS[gg][col]; Q += redQ[gg][col]; }
        atomicAdd(&segSum[seg * TWOF + col], S);
        atomicAdd(&segSumSq[seg * TWOF + col], Q);
    }
}

// ---------------- kernel 4: finalize mean / rsqrt(var+eps) in place ----------------
__global__ __launch_bounds__(256) void seg_finalize(
    const int* __restrict__ seg_start,
    float* __restrict__ segSum, float* __restrict__ segSumSq)
{
    int seg = blockIdx.x;
    int j = threadIdx.x;
    float cnt = (float)max(seg_start[seg + 1] - seg_start[seg], 1);
    float inv = 1.0f / cnt;
    float mean = segSum[seg * TWOF + j] * inv;
    float var  = segSumSq[seg * TWOF + j] * inv - mean * mean;
    segSum[seg * TWOF + j]   = mean;
    segSumSq[seg * TWOF + j] = rsqrtf(var + EPS_LN);
}

// ---------------- kernel 5: per-angle normalize + LN(core) + gate + scatter (v3) ----------------
// Vectorized reads (uint2 h, float4 params, half-wave reductions) + v1-style DENSE
// scatter: 8-shuffle transpose so lane j holds cols j and j+64, then two atomic
// instructions with 64 consecutive dwords each (lane-dense — avoids the 4x write
// amplification measured with per-lane strided atomics in R5).
__global__ __launch_bounds__(256) void angle_msg(
    const __hip_bfloat16* __restrict__ h,
    const int* __restrict__ seg_idx,
    const int* __restrict__ angle_nbr_idx,
    const float* __restrict__ segMean, const float* __restrict__ segScale,
    const float* __restrict__ cn_gamma, const float* __restrict__ cn_beta,
    const float* __restrict__ ln_g, const float* __restrict__ ln_b,
    const float* __restrict__ w_mask,
    float* __restrict__ s_acc, float* __restrict__ c_acc)
{
    int row  = blockIdx.x * 4 + (threadIdx.x >> 6);
    int lane = threadIdx.x & 63;
    int seg  = seg_idx[row];
    int src  = angle_nbr_idx[(size_t)row * 2];
    int c4   = lane * 4;

    uint2 hv = *(const uint2*)((const unsigned short*)h + (size_t)row * TWOF + c4);
    float y[4];
    y[0] = __uint_as_float(hv.x << 16);
    y[1] = __uint_as_float(hv.x & 0xffff0000u);
    y[2] = __uint_as_float(hv.y << 16);
    y[3] = __uint_as_float(hv.y & 0xffff0000u);

    float4 m4 = *(const float4*)&segMean[seg * TWOF + c4];
    float4 s4 = *(const float4*)&segScale[seg * TWOF + c4];
    float4 g4 = *(const float4*)&cn_gamma[c4];
    float4 b4 = *(const float4*)&cn_beta[c4];
    y[0] = (y[0] - m4.x) * s4.x * g4.x + b4.x;
    y[1] = (y[1] - m4.y) * s4.y * g4.y + b4.y;
    y[2] = (y[2] - m4.z) * s4.z * g4.z + b4.z;
    y[3] = (y[3] - m4.w) * s4.w * g4.w + b4.w;

    float sum, ssq, gp;
    if (lane < 32) {
        sum = y[0] + y[1] + y[2] + y[3];
        ssq = y[0]*y[0] + y[1]*y[1] + y[2]*y[2] + y[3]*y[3];
        gp  = 0.f;
    } else {
        float4 wm = *(const float4*)&w_mask[c4 - 128];
        gp  = y[0]*wm.x + y[1]*wm.y + y[2]*wm.z + y[3]*wm.w;
        sum = 0.f; ssq = 0.f;
    }
    #pragma unroll
    for (int o = 16; o > 0; o >>= 1) {
        sum += __shfl_xor(sum, o, 64);
        ssq += __shfl_xor(ssq, o, 64);
        gp  += __shfl_xor(gp,  o, 64);
    }
    float gate = 1.f / (1.f + __expf(-__shfl(gp, 32, 64)));

    // msg values (valid in lanes 0-31; cols c4..c4+3)
    float msgv[4] = {0.f, 0.f, 0.f, 0.f};
    if (lane < 32) {
        float mu  = sum * (1.f / 128.f);
        float var = ssq * (1.f / 128.f) - mu * mu;
        float rs  = rsqrtf(var + EPS_LN);
        float4 lg = *(const float4*)&ln_g[c4];
        float4 lb = *(const float4*)&ln_b[c4];
        float l0 = (y[0] - mu) * rs * lg.x + lb.x;
        float l1 = (y[1] - mu) * rs * lg.y + lb.y;
        float l2 = (y[2] - mu) * rs * lg.z + lb.z;
        float l3 = (y[3] - mu) * rs * lg.w + lb.w;
        msgv[0] = gate * (l0 / (1.f + __expf(-l0)));
        msgv[1] = gate * (l1 / (1.f + __expf(-l1)));
        msgv[2] = gate * (l2 / (1.f + __expf(-l2)));
        msgv[3] = gate * (l3 / (1.f + __expf(-l3)));
    }

    // transpose: lane j <- col j (from lane j>>2) and col 64+j (from lane 16+(j>>2))
    int srcl = lane >> 2;
    int e    = lane & 3;
    float t0 = __shfl(msgv[0], srcl, 64);
    float t1 = __shfl(msgv[1], srcl, 64);
    float t2 = __shfl(msgv[2], srcl, 64);
    float t3 = __shfl(msgv[3], srcl, 64);
    float out0 = (e == 0) ? t0 : (e == 1) ? t1 : (e == 2) ? t2 : t3;
    float u0 = __shfl(msgv[0], 16 + srcl, 64);
    float u1 = __shfl(msgv[1], 16 + srcl, 64);
    float u2 = __shfl(msgv[2], 16 + srcl, 64);
    float u3 = __shfl(msgv[3], 16 + srcl, 64);
    float out1 = (e == 0) ? u0 : (e == 1) ? u1 : (e == 2) ? u2 : u3;

    float* d = &s_acc[(size_t)src * NF];
    atomicAdd(d + lane, out0);
    atomicAdd(d + 64 + lane, out1);
    if (lane == 0) atomicAdd(&c_acc[src], 1.0f);
}

// ---------------- kernel 6: edge MLP via bf16 MFMA ----------------
#define MT 64
#define XBS 136
#define H1S 72
#define W1S 136
#define W2S 72
__global__ __launch_bounds__(256) void edge_mlp_mfma(
    const float* __restrict__ s_acc, const float* __restrict__ c_acc,
    const float* __restrict__ nbr_fea,
    const float* __restrict__ ln2_g, const float* __restrict__ ln2_b,
    const float* __restrict__ W1a, const float* __restrict__ b1a,
    const float* __restrict__ W2a, const float* __restrict__ b2a,
    const float* __restrict__ W1b, const float* __restrict__ b1b,
    const float* __restrict__ W2b, const float* __restrict__ b2b,
    float* __restrict__ out)
{
    __shared__ unsigned short xb[MT * XBS];
    __shared__ unsigned short h1[MT * H1S];
    __shared__ unsigned short wl[128 * W2S];

    const int tid  = threadIdx.x;
    const int row0 = blockIdx.x * MT;
    const int w    = tid >> 6, lane = tid & 63;
    const int rl   = lane & 15, kgrp = lane >> 4;

    {
        int m = tid >> 2;
        int q = tid & 3;
        int e = min(row0 + m, N_EDGES - 1);
        float inv = 1.f / fmaxf(c_acc[e], 1.f);
        const float4* src = (const float4*)(s_acc + (size_t)e * NF + q * 32);
        float v[32];
        float sum = 0.f, ssq = 0.f;
        #pragma unroll
        for (int t = 0; t < 8; ++t) {
            float4 f = src[t];
            v[4*t+0] = f.x * inv; v[4*t+1] = f.y * inv; v[4*t+2] = f.z * inv; v[4*t+3] = f.w * inv;
        }
        #pragma unroll
        for (int i = 0; i < 32; ++i) { sum += v[i]; ssq += v[i] * v[i]; }
        sum += __shfl_xor(sum, 1, 64); ssq += __shfl_xor(ssq, 1, 64);
        sum += __shfl_xor(sum, 2, 64); ssq += __shfl_xor(ssq, 2, 64);
        float mu  = sum * (1.f / 128.f);
        float var = ssq * (1.f / 128.f) - mu * mu;
        float rs  = rsqrtf(var + EPS_LN);
        #pragma unroll
        for (int i = 0; i < 32; ++i) {
            int col = q * 32 + i;
            v[i] = (v[i] - mu) * rs * ln2_g[col] + ln2_b[col];
        }
        #pragma unroll
        for (int t = 0; t < 4; ++t) {
            float4 a = make_float4(v[8*t+0], v[8*t+1], v[8*t+2], v[8*t+3]);
            float4 b = make_float4(v[8*t+4], v[8*t+5], v[8*t+6], v[8*t+7]);
            *(uint4*)&xb[m * XBS + q * 32 + t * 8] = cvt8(a, b);
        }
    }

    const float* W1s[2] = {W1a, W1b};
    const float* B1s[2] = {b1a, b1b};
    const float* W2s[2] = {W2a, W2b};
    const float* B2s[2] = {b2a, b2b};

    #pragma unroll 1
    for (int blk = 0; blk < 2; ++blk) {
        const float* W1 = W1s[blk]; const float* B1 = B1s[blk];
        const float* W2 = W2s[blk]; const float* B2 = B2s[blk];

        __syncthreads();
        #pragma unroll
        for (int c = tid; c < 1024; c += 256) {
            int nn = c >> 4, kc = c & 15;
            const float* src = W1 + (size_t)nn * 128 + kc * 8;
            *(uint4*)&wl[nn * W1S + kc * 8] =
                cvt8(((const float4*)src)[0], ((const float4*)src)[1]);
        }
        __syncthreads();

        short8 xf[4];
        #pragma unroll
        for (int ks = 0; ks < 4; ++ks)
            xf[ks] = *(const short8*)&xb[(w * 16 + rl) * XBS + ks * 32 + kgrp * 8];
        floatx4 a1[4];
        #pragma unroll
        for (int i = 0; i < 4; ++i) {
            a1[i] = (floatx4){0.f, 0.f, 0.f, 0.f};
            #pragma unroll
            for (int ks = 0; ks < 4; ++ks) {
                short8 wf = *(const short8*)&wl[(i * 16 + rl) * W1S + ks * 32 + kgrp * 8];
                a1[i] = __builtin_amdgcn_mfma_f32_16x16x32_bf16(wf, xf[ks], a1[i], 0, 0, 0);
            }
        }
        #pragma unroll
        for (int i = 0; i < 4; ++i) {
            int nb = i * 16 + kgrp * 4;
            float s0 = a1[i][0] + B1[nb + 0];
            float s1 = a1[i][1] + B1[nb + 1];
            float s2 = a1[i][2] + B1[nb + 2];
            float s3 = a1[i][3] + B1[nb + 3];
            s0 = s0 / (1.f + __expf(-s0));
            s1 = s1 / (1.f + __expf(-s1));
            s2 = s2 / (1.f + __expf(-s2));
            s3 = s3 / (1.f + __expf(-s3));
            unsigned int lo = (unsigned int)f2bf(s0) | ((unsigned int)f2bf(s1) << 16);
            unsigned int hi = (unsigned int)f2bf(s2) | ((unsigned int)f2bf(s3) << 16);
            *(unsigned int*)&h1[(w * 16 + rl) * H1S + nb]     = lo;
            *(unsigned int*)&h1[(w * 16 + rl) * H1S + nb + 2] = hi;
        }

        __syncthreads();
        #pragma unroll
        for (int c = tid; c < 1024; c += 256) {
            int pp = c >> 3, kc = c & 7;
            const float* src = W2 + (size_t)pp * 64 + kc * 8;
            *(uint4*)&wl[pp * W2S + kc * 8] =
                cvt8(((const float4*)src)[0], ((const float4*)src)[1]);
        }
        __syncthreads();

        short8 hf[2];
        #pragma unroll
        for (int ks = 0; ks < 2; ++ks)
            hf[ks] = *(const short8*)&h1[(w * 16 + rl) * H1S + ks * 32 + kgrp * 8];
        #pragma unroll
        for (int p = 0; p < 8; ++p) {
            floatx4 a2 = (floatx4){0.f, 0.f, 0.f, 0.f};
            #pragma unroll
            for (int ks = 0; ks < 2; ++ks) {
                short8 wf = *(const short8*)&wl[(p * 16 + rl) * W2S + ks * 32 + kgrp * 8];
                a2 = __builtin_amdgcn_mfma_f32_16x16x32_bf16(wf, hf[ks], a2, 0, 0, 0);
            }
            int m = w * 16 + rl;
            #pragma unroll
            for (int reg = 0; reg < 4; ++reg) {
                int pcol = p * 16 + kgrp * 4 + reg;
                int idx  = m * XBS + pcol;
                float xv = bfbits2f(xb[idx]);
                xb[idx] = f2bf(xv + a2[reg] + B2[pcol]);
            }
        }
    }

    {
        int m = tid >> 2;
        int q = tid & 3;
        int e = row0 + m;
        if (e < N_EDGES) {
            const float4* nf = (const float4*)(nbr_fea + (size_t)e * NF + q * 32);
            float4* dst      = (float4*)(out + (size_t)e * NF + q * 32);
            #pragma unroll
            for (int t = 0; t < 8; ++t) {
                float4 f = nf[t];
                int col = q * 32 + 4 * t;
                dst[t] = make_float4(
                    INV_SQRT_2 * (f.x + bfbits2f(xb[m * XBS + col + 0])),
                    INV_SQRT_2 * (f.y + bfbits2f(xb[m * XBS + col + 1])),
                    INV_SQRT_2 * (f.z + bfbits2f(xb[m * XBS + col + 2])),
                    INV_SQRT_2 * (f.w + bfbits2f(xb[m * XBS + col + 3])));
            }
        }
    }
}

// ---------------- workspace layout (bytes) ----------------
//   [0,              524288)   segSum   (512*256 f32)  -> mean after finalize
//   [524288,        1048576)   segSumSq (512*256 f32)  -> scale after finalize
//   [1048576,      52248576)   s_acc    (100000*128 f32)
//   [52248576,     52648576)   c_acc    (100000 f32)
//   --- everything above zeroed each launch ---
//   [52648576,     52652672)   seg_start (513 i32, padded)
//   [52652672,    257452672)   h (400000*256 bf16)
//   [257452672,   257616512)   wsW (pre-packed bf16 W, 10 x 16 KB)

extern "C" void kernel_launch(void* const* d_in, const int* in_sizes, int n_in,
                              void* d_out, int out_size, void* d_ws, size_t ws_size,
                              hipStream_t stream) {
    const float* nbr_fea       = (const float*)d_in[0];
    const float* angle_fea     = (const float*)d_in[1];
    const int*   angle_nbr_idx = (const int*)d_in[2];
    const int*   cai           = (const int*)d_in[4];
    const float* W_full        = (const float*)d_in[5];
    const float* W_mask        = (const float*)d_in[6];
    const float* cn_gamma      = (const float*)d_in[7];
    const float* cn_beta       = (const float*)d_in[8];
    const float* ln_core_g     = (const float*)d_in[9];
    const float* ln_core_b     = (const float*)d_in[10];
    const float* ln2_g         = (const float*)d_in[11];
    const float* ln2_b         = (const float*)d_in[12];
    const float* W1a           = (const float*)d_in[13];
    const float* b1a           = (const float*)d_in[14];
    const float* W2a           = (const float*)d_in[15];
    const float* b2a           = (const float*)d_in[16];
    const float* W1b           = (const float*)d_in[17];
    const float* b1b           = (const float*)d_in[18];
    const float* W2b           = (const float*)d_in[19];
    const float* b2b           = (const float*)d_in[20];
    float* out = (float*)d_out;

    char* ws = (char*)d_ws;
    float* segSum    = (float*)(ws + 0);
    float* segSumSq  = (float*)(ws + 524288);
    float* s_acc     = (float*)(ws + 1048576);
    float* c_acc     = (float*)(ws + 52248576);
    int*   seg_start = (int*)  (ws + 52648576);
    __hip_bfloat16* h = (__hip_bfloat16*)(ws + 52652672);
    uint4* wsW       = (uint4*)(ws + 257452672);

    hipMemsetAsync(ws, 0, 52648576, stream);

    w_pack<<<40, 256, 0, stream>>>(W_full, wsW);
    seg_bounds<<<3, 256, 0, stream>>>(cai, seg_start);
    gemm_gather_mfma<<<N_ANGLES / 64, 256, 0, stream>>>(
        angle_fea, nbr_fea, angle_nbr_idx, wsW, h);
    seg_stats<<<dim3(N_CRYST, 4), 256, 0, stream>>>(h, seg_start, segSum, segSumSq);
    seg_finalize<<<N_CRYST, 256, 0, stream>>>(seg_start, segSum, segSumSq);
    angle_msg<<<N_ANGLES / 4, 256, 0, stream>>>(
        h, cai, angle_nbr_idx, segSum, segSumSq,
        cn_gamma, cn_beta, ln_core_g, ln_core_b, W_mask, s_acc, c_acc);
    edge_mlp_mfma<<<(N_EDGES + MT - 1) / MT, 256, 0, stream>>>(
        s_acc, c_acc, nbr_fea, ln2_g, ln2_b,
        W1a, b1a, W2a, b2a, W1b, b1b, W2b, b2b, out);
}